// Round 8
// baseline (298.721 us; speedup 1.0000x reference)
//
#include <hip/hip_runtime.h>
#include <hip/hip_bf16.h>
#include <hip/hip_fp16.h>

// SparseGAT forward. fp16-MFMA feature transform (128-row tile, wave-per-head,
// fused transpose + aw); CSR edge pipeline, 16-lane-group rows, 4-edge-deep
// pipelined gather, packed-fp16 ex broadcast, balanced persistent blocks.
// N=50000, FI=256, FO=64, H=8, E=800000, avg deg 16.
//
// Th2 [n][f*8+h] head-minor fp16 (1KB/row).
// ws: Th2[N*512]f16 | Wth[8*64*256]f16 | aw[N*8]f32 | deg[N] | row_start[N+4]
//     | cursor[N] | colperm[E] | blocksums[64]

#define FI 256
#define FO 64
#define NH 8
#define FC 512
#define BM 128

typedef _Float16 f16x8 __attribute__((ext_vector_type(8)));
typedef float f32x16 __attribute__((ext_vector_type(16)));
typedef float f32x8 __attribute__((ext_vector_type(8)));
typedef float f32x4 __attribute__((ext_vector_type(4)));

// ---------------- P1: W[h][k][f] -> Wth[h][f][k] fp16 -----------------------
__global__ __launch_bounds__(256)
void p1_wconv(const float* __restrict__ W, _Float16* __restrict__ Wth) {
  int idx = blockIdx.x * 256 + threadIdx.x;   // h*64*256 + f*256 + k
  if (idx >= NH * FO * FI) return;
  int k = idx & (FI - 1);
  int f = (idx >> 8) & (FO - 1);
  int h = idx >> 14;
  Wth[idx] = (_Float16)W[((size_t)h * FI + k) * FO + f];
}

// ---------------- K1v2: 128-row tile, wave = head ---------------------------
__global__ __launch_bounds__(512)
void k1_v2(const float* __restrict__ x, const _Float16* __restrict__ Wth,
           const float* __restrict__ a, _Float16* __restrict__ Th2,
           float* __restrict__ aw, int N) {
  __shared__ _Float16 smem[BM * 136];            // 34.8 KB, aliased Xs / Tt
  auto Xs = reinterpret_cast<_Float16(*)[136]>(smem);   // [128][136]
  auto Tt = reinterpret_cast<_Float16(*)[512]>(smem);   // [32][512]
  const int bm = blockIdx.x * BM;
  const int t = threadIdx.x;
  const int w = t >> 6;             // wave id = head
  const int lane = t & 63;
  const int l31 = lane & 31;
  const int kh = (lane >> 5) * 8;
  const _Float16* Wh = Wth + (size_t)w * (FO * FI);

  f32x16 acc[4][2];
  #pragma unroll
  for (int mr = 0; mr < 4; ++mr)
    #pragma unroll
    for (int wc = 0; wc < 2; ++wc) acc[mr][wc] = (f32x16)0.0f;

  #pragma unroll
  for (int k0 = 0; k0 < 2; ++k0) {
    if (k0) __syncthreads();
    #pragma unroll
    for (int r = 0; r < 8; ++r) {
      int i = t + r * 512;          // 0..4095
      int row = i >> 5;             // 32 float4 per row
      int q = i & 31;
      float4 v = make_float4(0.f, 0.f, 0.f, 0.f);
      if (bm + row < N)
        v = reinterpret_cast<const float4*>(&x[(size_t)(bm + row) * FI + k0 * 128])[q];
      _Float16 o[4] = {(_Float16)v.x, (_Float16)v.y, (_Float16)v.z, (_Float16)v.w};
      *reinterpret_cast<uint2*>(&Xs[row][q * 4]) = *reinterpret_cast<uint2*>(o);
    }
    __syncthreads();
    #pragma unroll
    for (int kk = 0; kk < 8; ++kk) {
      f16x8 af[4], bf[2];
      #pragma unroll
      for (int mr = 0; mr < 4; ++mr)
        af[mr] = *reinterpret_cast<const f16x8*>(&Xs[mr * 32 + l31][kk * 16 + kh]);
      #pragma unroll
      for (int wc = 0; wc < 2; ++wc)
        bf[wc] = *reinterpret_cast<const f16x8*>(
            &Wh[(size_t)(wc * 32 + l31) * FI + k0 * 128 + kk * 16 + kh]);
      #pragma unroll
      for (int mr = 0; mr < 4; ++mr)
        #pragma unroll
        for (int wc = 0; wc < 2; ++wc)
          acc[mr][wc] =
              __builtin_amdgcn_mfma_f32_32x32x16_f16(af[mr], bf[wc], acc[mr][wc], 0, 0, 0);
    }
  }

  // aw[n][w] = sum_f T[n][w][f] * a[w][f]
  const float av0 = a[w * FO + l31], av1 = a[w * FO + 32 + l31];
  #pragma unroll
  for (int mr = 0; mr < 4; ++mr)
    #pragma unroll
    for (int reg = 0; reg < 16; ++reg) {
      float s = acc[mr][0][reg] * av0 + acc[mr][1][reg] * av1;
      #pragma unroll
      for (int off = 1; off < 32; off <<= 1) s += __shfl_xor(s, off);
      if (l31 == 0) {
        int rl = mr * 32 + (reg & 3) + 8 * (reg >> 2) + 4 * (lane >> 5);
        if (bm + rl < N) aw[(size_t)(bm + rl) * NH + w] = s;
      }
    }

  // Th2: transpose 32-row chunks through LDS, coalesced 16B stores
  #pragma unroll
  for (int ch = 0; ch < 4; ++ch) {
    __syncthreads();
    #pragma unroll
    for (int wc = 0; wc < 2; ++wc) {
      const int f = wc * 32 + l31;
      #pragma unroll
      for (int reg = 0; reg < 16; ++reg) {
        int rl = (reg & 3) + 8 * (reg >> 2) + 4 * (lane >> 5);
        Tt[rl][f * NH + w] = (_Float16)acc[ch][wc][reg];
      }
    }
    __syncthreads();
    #pragma unroll
    for (int r = 0; r < 4; ++r) {
      int i = t + r * 512;          // 0..2047
      int row = i >> 6, q = i & 63;
      int grow = bm + ch * 32 + row;
      if (grow < N)
        *reinterpret_cast<uint4*>(&Th2[(size_t)grow * FC + q * 8]) =
            *reinterpret_cast<const uint4*>(&Tt[row][q * 8]);
    }
  }
}

// ---------------- B1: degree histogram --------------------------------------
__global__ __launch_bounds__(256)
void b1_hist(const int* __restrict__ rows, int* __restrict__ deg, int E) {
  int e = blockIdx.x * 256 + threadIdx.x;
  if (e < E) atomicAdd(&deg[rows[e]], 1);
}

// ---------------- B2a: per-block sums (1024 elems/block) --------------------
__global__ __launch_bounds__(256)
void b2a_blocksum(const int* __restrict__ deg, int* __restrict__ blocksums, int N) {
  __shared__ int red[256];
  const int t = threadIdx.x;
  const int base = blockIdx.x * 1024 + t * 4;
  int s = 0;
  #pragma unroll
  for (int j = 0; j < 4; ++j) { int i = base + j; if (i < N) s += deg[i]; }
  red[t] = s;
  __syncthreads();
  for (int off = 128; off; off >>= 1) {
    if (t < off) red[t] += red[t + off];
    __syncthreads();
  }
  if (t == 0) blocksums[blockIdx.x] = red[0];
}

// ---------------- B2b: exclusive scan of block sums (1 wave) ----------------
__global__ __launch_bounds__(64)
void b2b_scanblocks(int* __restrict__ blocksums, int nb,
                    int* __restrict__ row_start, int N, int E) {
  const int lane = threadIdx.x;
  int carry = 0;
  for (int base = 0; base < nb; base += 64) {
    int i = base + lane;
    int v = (i < nb) ? blocksums[i] : 0;
    int inc = v;
    #pragma unroll
    for (int off = 1; off < 64; off <<= 1) {
      int t = __shfl_up(inc, off);
      if (lane >= off) inc += t;
    }
    if (i < nb) blocksums[i] = inc - v + carry;  // exclusive
    carry += __shfl(inc, 63);
  }
  if (lane == 0) row_start[N] = E;
}

// ---------------- B2c: per-block rescan -> row_start, cursor ----------------
__global__ __launch_bounds__(256)
void b2c_rescan(const int* __restrict__ deg, const int* __restrict__ blocksums,
                int* __restrict__ row_start, int* __restrict__ cursor, int N) {
  __shared__ int ts[256];
  const int t = threadIdx.x;
  const int base = blockIdx.x * 1024 + t * 4;
  int v[4]; int s = 0;
  #pragma unroll
  for (int j = 0; j < 4; ++j) { int i = base + j; v[j] = (i < N) ? deg[i] : 0; s += v[j]; }
  ts[t] = s;
  __syncthreads();
  for (int off = 1; off < 256; off <<= 1) {
    int add = (t >= off) ? ts[t - off] : 0;
    __syncthreads();
    ts[t] += add;
    __syncthreads();
  }
  int run = blocksums[blockIdx.x] + ts[t] - s;
  #pragma unroll
  for (int j = 0; j < 4; ++j) {
    int i = base + j;
    if (i < N) { row_start[i] = run; cursor[i] = run; run += v[j]; }
  }
}

// ---------------- B3: scatter cols into CSR order ---------------------------
__global__ __launch_bounds__(256)
void b3_scatter(const int* __restrict__ rows, const int* __restrict__ cols,
                int* __restrict__ cursor, int* __restrict__ colperm, int E) {
  int e = blockIdx.x * 256 + threadIdx.x;
  if (e >= E) return;
  int pos = atomicAdd(&cursor[rows[e]], 1);
  colperm[pos] = cols[e];
}

// ---------------- K4: fused softmax + aggregation ---------------------------
// 16-lane group per row; 4-edge-deep pipelined gather (2 pair buffers);
// ex broadcast as packed fp16 (4 shfl/edge); persistent balanced blocks.
__global__ __launch_bounds__(256)
void k4_fused(const int* __restrict__ row_start, const int* __restrict__ colperm,
              const float* __restrict__ aw, const _Float16* __restrict__ Th2,
              const float* __restrict__ b, float* __restrict__ out, int N) {
  const int lane16 = threadIdx.x & 15;
  const int gbase  = threadIdx.x & 48;       // group base lane within wave
  const int ntiles = (N + 15) / 16;

  for (int tile = blockIdx.x; tile < ntiles; tile += gridDim.x) {
    const int r = tile * 16 + (threadIdx.x >> 4);
    if (r >= N) continue;

    const int s0 = row_start[r], s1 = row_start[r + 1];
    f32x8 awr = *reinterpret_cast<const f32x8*>(&aw[(size_t)r * NH]);

    float facc[4][NH] = {};
    float dacc[NH] = {};

    for (int base = s0; base < s1; base += 16) {
      const int mm = min(16, s1 - base);
      const bool valid = lane16 < mm;
      int c_l = valid ? colperm[base + lane16] : 0;

      f32x8 awc = *reinterpret_cast<const f32x8*>(&aw[(size_t)c_l * NH]);
      float ex[NH];
      uint32_t pk[4];
      #pragma unroll
      for (int h = 0; h < NH; ++h) {
        float s = awr[h] + awc[h];
        float lr = s > 0.f ? s : 0.2f * s;
        ex[h] = valid ? __expf(lr) : 0.f;
        dacc[h] += ex[h];
      }
      #pragma unroll
      for (int q = 0; q < 4; ++q) {
        __half2 h2 = __floats2half2_rn(ex[2 * q], ex[2 * q + 1]);
        pk[q] = *reinterpret_cast<uint32_t*>(&h2);
      }

      // 4-edge pipeline: pair buffers A (compute) / B (loading)
      f16x8 A0[4], A1[4], B0[4], B1[4];
      {
        int c0 = __shfl(c_l, gbase + 0);
        int c1 = __shfl(c_l, gbase + 1);
        const _Float16* t0 = Th2 + (size_t)c0 * FC + lane16 * NH;
        const _Float16* t1 = Th2 + (size_t)c1 * FC + lane16 * NH;
        #pragma unroll
        for (int q = 0; q < 4; ++q) {
          A0[q] = *reinterpret_cast<const f16x8*>(t0 + q * 128);
          A1[q] = *reinterpret_cast<const f16x8*>(t1 + q * 128);
        }
      }
      for (int j = 0; j < mm; j += 2) {
        if (j + 2 < mm) {
          int c0 = __shfl(c_l, gbase + j + 2);
          int c1 = __shfl(c_l, gbase + j + 3);
          const _Float16* t0 = Th2 + (size_t)c0 * FC + lane16 * NH;
          const _Float16* t1 = Th2 + (size_t)c1 * FC + lane16 * NH;
          #pragma unroll
          for (int q = 0; q < 4; ++q) {
            B0[q] = *reinterpret_cast<const f16x8*>(t0 + q * 128);
            B1[q] = *reinterpret_cast<const f16x8*>(t1 + q * 128);
          }
        }
        float e0[NH], e1[NH];
        #pragma unroll
        for (int q = 0; q < 4; ++q) {
          int p = __shfl((int)pk[q], gbase + j);
          float2 f2 = __half22float2(*reinterpret_cast<__half2*>(&p));
          e0[2 * q] = f2.x; e0[2 * q + 1] = f2.y;
        }
        #pragma unroll
        for (int q = 0; q < 4; ++q) {
          int p = __shfl((int)pk[q], gbase + j + 1);
          float2 f2 = __half22float2(*reinterpret_cast<__half2*>(&p));
          e1[2 * q] = f2.x; e1[2 * q + 1] = f2.y;
        }
        #pragma unroll
        for (int q = 0; q < 4; ++q)
          #pragma unroll
          for (int h = 0; h < NH; ++h)
            facc[q][h] = fmaf(e0[h], (float)A0[q][h], facc[q][h]);
        if (j + 1 < mm) {
          #pragma unroll
          for (int q = 0; q < 4; ++q)
            #pragma unroll
            for (int h = 0; h < NH; ++h)
              facc[q][h] = fmaf(e1[h], (float)A1[q][h], facc[q][h]);
        }
        #pragma unroll
        for (int q = 0; q < 4; ++q) { A0[q] = B0[q]; A1[q] = B1[q]; }
      }
    }

    #pragma unroll
    for (int h = 0; h < NH; ++h) {
      #pragma unroll
      for (int off = 1; off < 16; off <<= 1)
        dacc[h] += __shfl_xor(dacc[h], off);
    }

    float rden[NH];
    #pragma unroll
    for (int h = 0; h < NH; ++h) rden[h] = dacc[h] > 0.f ? 1.0f / dacc[h] : 0.f;

    #pragma unroll
    for (int q = 0; q < 4; ++q) {
      const int f = q * 16 + lane16;
      float sb = 0.f;
      #pragma unroll
      for (int h = 0; h < NH; ++h) sb += b[h * FO + f];
      float v = 0.f;
      #pragma unroll
      for (int h = 0; h < NH; ++h) v += facc[q][h] * rden[h];
      v = (v + sb) * 0.125f;
      out[(size_t)r * FO + f] = v > 0.f ? v : 0.f;
    }
  }
}

extern "C" void kernel_launch(void* const* d_in, const int* in_sizes, int n_in,
                              void* d_out, int out_size, void* d_ws, size_t ws_size,
                              hipStream_t stream) {
  const float* x    = (const float*)d_in[0];
  const float* W    = (const float*)d_in[1];
  const float* a    = (const float*)d_in[2];
  const float* b    = (const float*)d_in[3];
  const int*   rows = (const int*)d_in[4];
  const int*   cols = (const int*)d_in[5];
  const int N = in_sizes[0] / FI;
  const int E = in_sizes[4];

  char* p = (char*)d_ws;
  _Float16* Th2      = (_Float16*)p;  p += (size_t)N * FC * sizeof(_Float16);
  _Float16* Wth      = (_Float16*)p;  p += (size_t)NH * FO * FI * sizeof(_Float16);
  float*    aw       = (float*)p;     p += (size_t)N * NH * sizeof(float);
  int*      deg      = (int*)p;       p += (size_t)N * sizeof(int);
  int*      row_start= (int*)p;       p += (size_t)(N + 4) * sizeof(int);
  int*      cursor   = (int*)p;       p += (size_t)N * sizeof(int);
  int*      colperm  = (int*)p;       p += (size_t)E * sizeof(int);
  int*      blocksums= (int*)p;       p += 64 * sizeof(int);
  float*    out = (float*)d_out;

  const int nb = (N + 1023) / 1024;

  // CSR build
  hipMemsetAsync(deg, 0, (size_t)N * sizeof(int), stream);
  b1_hist<<<(E + 255) / 256, 256, 0, stream>>>(rows, deg, E);
  b2a_blocksum<<<nb, 256, 0, stream>>>(deg, blocksums, N);
  b2b_scanblocks<<<1, 64, 0, stream>>>(blocksums, nb, row_start, N, E);
  b2c_rescan<<<nb, 256, 0, stream>>>(deg, blocksums, row_start, cursor, N);
  b3_scatter<<<(E + 255) / 256, 256, 0, stream>>>(rows, cols, cursor, colperm, E);

  // dense feature transform (all heads, fused transpose + aw)
  p1_wconv<<<(NH * FO * FI + 255) / 256, 256, 0, stream>>>(W, Wth);
  k1_v2<<<(N + BM - 1) / BM, 512, 0, stream>>>(x, Wth, a, Th2, aw, N);

  // fused edge pipeline: persistent blocks, 2 tiles each
  const int ntiles = (N + 15) / 16;
  const int grid4 = (ntiles + 1) / 2;
  k4_fused<<<grid4, 256, 0, stream>>>(row_start, colperm, aw, Th2, b, out, N);
}